// Round 11
// baseline (517.819 us; speedup 1.0000x reference)
//
#include <hip/hip_runtime.h>
#include <math.h>

#define NN 100000
#define FEAT 128
#define NHEAD 4
#define BSH 9                      // 512 nodes per bucket
#define BNODES 512
#define NBUCK 196                  // ceil(NN / 512)
#define BCAP 16384                 // colidx LDS image capacity (avg span ~8700)
#define PA_EPT 16                  // phase-A edges per thread
#define GTILES 6250                // 100000 / 16
#define HSTRIDE 136                // h-staging row stride (ushorts): 272B = 16B-aligned, bank-rotated

typedef unsigned int uint;
typedef unsigned short ushort;
typedef __attribute__((ext_vector_type(8))) short short8;
typedef __attribute__((ext_vector_type(4))) float fx4;

__device__ __forceinline__ float lrelu(float v) { return v > 0.f ? v : 0.2f * v; }

__device__ __forceinline__ ushort f2bf(float f) {          // RNE bf16
    uint u = __float_as_uint(f);
    return (ushort)((u + 0x7fffu + ((u >> 16) & 1u)) >> 16);
}
__device__ __forceinline__ float bf_lo(uint u) { return __uint_as_float(u << 16); }
__device__ __forceinline__ float bf_hi(uint u) { return __uint_as_float(u & 0xffff0000u); }

// ---- fp32 -> bf16 convert (layer-0 input) ----
__global__ __launch_bounds__(256) void convert_bf_kernel(
    const float* __restrict__ x, ushort* __restrict__ xbf)
{
    int i = blockIdx.x * 256 + threadIdx.x;
    if (i >= NN * FEAT / 4) return;
    float4 v = ((const float4*)x)[i];
    ushort4 u;
    u.x = f2bf(v.x); u.y = f2bf(v.y); u.z = f2bf(v.z); u.w = f2bf(v.w);
    ((ushort4*)xbf)[i] = u;
}

// ---- MFMA GEMM: h(bf16) = in(bf16) @ W, + per-node logits al_src/al_dst ----
// A = W^T cached in VGPRs; LDS store-staging for full-line h writes (r9);
// NEW: next-tile B prefetch to hide global load latency behind MFMA+epilogue.
__global__ __launch_bounds__(256, 2) void gemm_mfma_kernel(
    const ushort* __restrict__ inbf, const float* __restrict__ W,
    const float* __restrict__ a_src, const float* __restrict__ a_dst,
    ushort* __restrict__ hbf, float* __restrict__ al_s, float* __restrict__ al_d)
{
    __shared__ __align__(16) ushort WA[FEAT * FEAT];       // 32 KiB, fragment-ordered
    __shared__ __align__(16) ushort HS[4][16 * HSTRIDE];   // 17 KiB, per-wave h staging
    const int t = threadIdx.x;
    for (int idx = t; idx < FEAT * FEAT; idx += 256) {
        int k = idx >> 7, m = idx & 127;
        int mt = m >> 4, kt = k >> 5, qq = (k >> 3) & 3, j = k & 7;
        int ln = qq * 16 + (m & 15);
        WA[((mt * 4 + kt) * 64 + ln) * 8 + j] = f2bf(W[idx]);
    }
    __syncthreads();

    const int wv = t >> 6, lane = t & 63;
    const int node_l = lane & 15, q = lane >> 4;

    short8 afr[8][4];
    #pragma unroll
    for (int mt = 0; mt < 8; ++mt)
        #pragma unroll
        for (int kt = 0; kt < 4; ++kt)
            afr[mt][kt] = *(const short8*)&WA[((mt * 4 + kt) * 64 + lane) * 8];

    const int stride = gridDim.x * 4;
    int tile = blockIdx.x * 4 + wv;
    if (tile >= GTILES) return;

    const ushort* rowp = inbf + (size_t)(tile * 16 + node_l) * FEAT + q * 8;
    short8 b0 = *(const short8*)(rowp);
    short8 b1 = *(const short8*)(rowp + 32);
    short8 b2 = *(const short8*)(rowp + 64);
    short8 b3 = *(const short8*)(rowp + 96);

    for (; tile < GTILES; tile += stride) {
        const int n0 = tile * 16;
        int ntile = tile + stride;
        short8 nb0, nb1, nb2, nb3;
        if (ntile < GTILES) {
            const ushort* nrp = inbf + (size_t)(ntile * 16 + node_l) * FEAT + q * 8;
            nb0 = *(const short8*)(nrp);
            nb1 = *(const short8*)(nrp + 32);
            nb2 = *(const short8*)(nrp + 64);
            nb3 = *(const short8*)(nrp + 96);
        }
        fx4 zero = {0.f, 0.f, 0.f, 0.f};
        fx4 acc[8];
        #pragma unroll
        for (int mt = 0; mt < 8; ++mt) acc[mt] = zero;
        #pragma unroll
        for (int kt = 0; kt < 4; ++kt) {
            short8 b = (kt == 0) ? b0 : (kt == 1) ? b1 : (kt == 2) ? b2 : b3;
            #pragma unroll
            for (int mt = 0; mt < 8; ++mt)
                acc[mt] = __builtin_amdgcn_mfma_f32_16x16x32_bf16(afr[mt][kt], b, acc[mt], 0, 0, 0);
        }
        // epilogue: logits + stage h into per-wave LDS tile
        float ps[4] = {0.f, 0.f, 0.f, 0.f};
        float pd[4] = {0.f, 0.f, 0.f, 0.f};
        #pragma unroll
        for (int mt = 0; mt < 8; ++mt) {
            float4 as4 = *(const float4*)(a_src + mt * 16 + q * 4);
            float4 ad4 = *(const float4*)(a_dst + mt * 16 + q * 4);
            ps[mt >> 1] += acc[mt][0] * as4.x + acc[mt][1] * as4.y + acc[mt][2] * as4.z + acc[mt][3] * as4.w;
            pd[mt >> 1] += acc[mt][0] * ad4.x + acc[mt][1] * ad4.y + acc[mt][2] * ad4.z + acc[mt][3] * ad4.w;
            ushort4 hv;
            hv.x = f2bf(acc[mt][0]); hv.y = f2bf(acc[mt][1]);
            hv.z = f2bf(acc[mt][2]); hv.w = f2bf(acc[mt][3]);
            *(ushort4*)&HS[wv][node_l * HSTRIDE + mt * 16 + q * 4] = hv;
        }
        #pragma unroll
        for (int h = 0; h < 4; ++h) {
            ps[h] += __shfl_xor(ps[h], 16); ps[h] += __shfl_xor(ps[h], 32);
            pd[h] += __shfl_xor(pd[h], 16); pd[h] += __shfl_xor(pd[h], 32);
        }
        float vs = (q == 0) ? ps[0] : (q == 1) ? ps[1] : (q == 2) ? ps[2] : ps[3];
        float vd = (q == 0) ? pd[0] : (q == 1) ? pd[1] : (q == 2) ? pd[2] : pd[3];
        al_s[(n0 + node_l) * 4 + q] = vs;
        al_d[(n0 + node_l) * 4 + q] = vd;
        // copy-out: wave-private LDS -> 4x fully-coalesced 1KB global stores
        #pragma unroll
        for (int it = 0; it < 4; ++it) {
            int fi = it * 64 + lane;               // 16B chunk index within tile
            int row = fi >> 4, colc = fi & 15;
            short8 v = *(const short8*)&HS[wv][row * HSTRIDE + colc * 8];
            *(short8*)(hbf + (size_t)n0 * FEAT + (size_t)fi * 8) = v;
        }
        b0 = nb0; b1 = nb1; b2 = nb2; b3 = nb3;
    }
}

// ======================= CSR build: bucketed counting sort =======================

__global__ void zero_small_kernel(int* bsize)
{
    int t = threadIdx.x;
    if (t < NBUCK) bsize[t] = 0;
}

__global__ __launch_bounds__(256) void bucket_hist_kernel(
    const int* __restrict__ ei, int E, int* bsize)
{
    __shared__ int lh[NBUCK];
    int t = threadIdx.x;
    if (t < NBUCK) lh[t] = 0;
    __syncthreads();
    int stride = gridDim.x * 256;
    for (int i = blockIdx.x * 256 + t; i < E + NN; i += stride) {
        int d = (i < E) ? ei[E + i] : (i - E);
        atomicAdd(&lh[d >> BSH], 1);
    }
    __syncthreads();
    if (t < NBUCK && lh[t]) atomicAdd(&bsize[t], lh[t]);
}

// parallel 256-wide LDS scan over NBUCK entries (was single-thread serial loop)
__global__ __launch_bounds__(256) void bucket_scan_kernel(
    const int* __restrict__ bsize, int* bbase, int* bcursor)
{
    __shared__ int sm[256];
    int t = threadIdx.x;
    int v = (t < NBUCK) ? bsize[t] : 0;
    sm[t] = v;
    __syncthreads();
    #pragma unroll
    for (int off = 1; off < 256; off <<= 1) {
        int x = (t >= off) ? sm[t - off] : 0;
        __syncthreads();
        sm[t] += x;
        __syncthreads();
    }
    if (t < NBUCK) {
        int excl = sm[t] - v;
        bbase[t] = excl;
        bcursor[t] = excl;
    }
    if (t == 255) bbase[NBUCK] = sm[255];
}

__global__ __launch_bounds__(256) void phaseA_bin_kernel(
    const int* __restrict__ ei, int E, int* bcursor, int2* __restrict__ pairs)
{
    __shared__ int lh[NBUCK], lb[NBUCK];
    int t = threadIdx.x;
    if (t < NBUCK) lh[t] = 0;
    __syncthreads();
    int base = blockIdx.x * (256 * PA_EPT) + t;
    int s[PA_EPT], d[PA_EPT];
    #pragma unroll
    for (int k = 0; k < PA_EPT; ++k) {
        int i = base + k * 256;
        if (i < E)            { s[k] = ei[i]; d[k] = ei[E + i]; }
        else if (i < E + NN)  { s[k] = i - E; d[k] = s[k]; }
        else                  { s[k] = 0; d[k] = -1; }
        if (d[k] >= 0) atomicAdd(&lh[d[k] >> BSH], 1);
    }
    __syncthreads();
    if (t < NBUCK) {
        int c = lh[t];
        lb[t] = c ? atomicAdd(&bcursor[t], c) : 0;
        lh[t] = 0;
    }
    __syncthreads();
    #pragma unroll
    for (int k = 0; k < PA_EPT; ++k) {
        if (d[k] >= 0) {
            int b = d[k] >> BSH;
            int off = atomicAdd(&lh[b], 1);
            pairs[lb[b] + off] = make_int2(d[k], s[k]);
        }
    }
}

__global__ __launch_bounds__(256) void phaseB_kernel(
    const int2* __restrict__ pairs, const int* __restrict__ bbase,
    int* __restrict__ row_ptr, int* __restrict__ colidx, int EP)
{
    __shared__ int nh[BNODES];
    __shared__ int ex[BNODES];
    __shared__ int ss[256];
    __shared__ int img[BCAP];
    int b = blockIdx.x, t = threadIdx.x;
    int node0 = b << BSH;
    int nend = min(NN - node0, BNODES);
    int pb = bbase[b], pe = bbase[b + 1];
    int span = pe - pb;
    for (int j = t; j < BNODES; j += 256) nh[j] = 0;
    __syncthreads();
    for (int i = t; i < span; i += 256)
        atomicAdd(&nh[pairs[pb + i].x - node0], 1);
    __syncthreads();
    int v0 = nh[2 * t], v1 = nh[2 * t + 1];
    int psc = v0 + v1;
    ss[t] = psc;
    __syncthreads();
    #pragma unroll
    for (int off = 1; off < 256; off <<= 1) {
        int x = (t >= off) ? ss[t - off] : 0;
        __syncthreads();
        ss[t] += x;
        __syncthreads();
    }
    int ep = ss[t] - psc;
    ex[2 * t] = ep;
    ex[2 * t + 1] = ep + v0;
    __syncthreads();
    for (int j = t; j < nend; j += 256) row_ptr[node0 + j] = pb + ex[j];
    if (b == NBUCK - 1 && t == 0) row_ptr[NN] = EP;
    for (int j = t; j < BNODES; j += 256) nh[j] = ex[j];   // reuse as cursors
    __syncthreads();
    if (span <= BCAP) {
        for (int i = t; i < span; i += 256) {
            int2 p = pairs[pb + i];
            int pos = atomicAdd(&nh[p.x - node0], 1);
            img[pos] = p.y;
        }
        __syncthreads();
        for (int i = t; i < span; i += 256) colidx[pb + i] = img[i];
    } else {
        for (int i = t; i < span; i += 256) {
            int2 p = pairs[pb + i];
            int pos = atomicAdd(&nh[p.x - node0], 1);
            colidx[pb + pos] = p.y;
        }
    }
}

// ======================= fused softmax + aggregation (bf16 out) =======================
#define AGGR_STEP(hv, wgt)                                                    \
    a0 = fmaf(wgt, bf_lo(hv.x), a0); a1 = fmaf(wgt, bf_hi(hv.x), a1);        \
    a2 = fmaf(wgt, bf_lo(hv.y), a2); a3 = fmaf(wgt, bf_hi(hv.y), a3);        \
    a4 = fmaf(wgt, bf_lo(hv.z), a4); a5 = fmaf(wgt, bf_hi(hv.z), a5);        \
    a6 = fmaf(wgt, bf_lo(hv.w), a6); a7 = fmaf(wgt, bf_hi(hv.w), a7);

#define PROC4(cv)                                                             \
    {                                                                         \
        int s0 = cv.x, s1 = cv.y, s2 = cv.z, s3 = cv.w;                       \
        float w0 = __expf(lrelu(al_s[s0*4 + head] + ald_h));                  \
        float w1 = __expf(lrelu(al_s[s1*4 + head] + ald_h));                  \
        float w2 = __expf(lrelu(al_s[s2*4 + head] + ald_h));                  \
        float w3 = __expf(lrelu(al_s[s3*4 + head] + ald_h));                  \
        uint4 h0 = ((const uint4*)(hbf + (size_t)s0 * FEAT))[lane];           \
        uint4 h1 = ((const uint4*)(hbf + (size_t)s1 * FEAT))[lane];           \
        uint4 h2 = ((const uint4*)(hbf + (size_t)s2 * FEAT))[lane];           \
        uint4 h3 = ((const uint4*)(hbf + (size_t)s3 * FEAT))[lane];           \
        ssum += (w0 + w1) + (w2 + w3);                                        \
        AGGR_STEP(h0, w0) AGGR_STEP(h1, w1) AGGR_STEP(h2, w2) AGGR_STEP(h3, w3) \
    }

__global__ __launch_bounds__(256) void aggr_csr_kernel(
    const int* __restrict__ row_ptr, const int* __restrict__ colidx,
    const ushort* __restrict__ hbf, const float* __restrict__ al_s,
    const float* __restrict__ al_d, const float* __restrict__ bias,
    ushort* __restrict__ outbf)
{
    int t = threadIdx.x;
    int node = blockIdx.x * 16 + (t >> 4);
    if (node >= NN) return;
    int lane = t & 15;
    int head = lane >> 2;
    float ald_h = al_d[node * 4 + head];
    int beg = row_ptr[node], end = row_ptr[node + 1];

    float ssum = 0.f;
    float a0=0.f,a1=0.f,a2=0.f,a3=0.f,a4=0.f,a5=0.f,a6=0.f,a7=0.f;

    int p = beg;
    int4 ca;
    if (p + 4 <= end) ca = *(const int4*)&colidx[p];
    while (p + 8 <= end) {
        int4 na = *(const int4*)&colidx[p + 4];   // prefetch next batch
        PROC4(ca)
        ca = na;
        p += 4;
    }
    if (p + 4 <= end) { PROC4(ca) p += 4; }
    for (; p < end; ++p) {
        int sn = colidx[p];
        float wq = __expf(lrelu(al_s[sn*4 + head] + ald_h));
        uint4 hv = ((const uint4*)(hbf + (size_t)sn * FEAT))[lane];
        ssum += wq;
        AGGR_STEP(hv, wq)
    }
    float inv = 1.f / (ssum + 1e-16f);
    const float* bp = bias + lane * 8;
    float o[8] = {a0,a1,a2,a3,a4,a5,a6,a7};
    #pragma unroll
    for (int k = 0; k < 8; ++k) {
        float v = o[k] * inv + bp[k];
        o[k] = v > 0.f ? v : __expf(v) - 1.f;
    }
    uint4 u;
    u.x = (uint)f2bf(o[0]) | ((uint)f2bf(o[1]) << 16);
    u.y = (uint)f2bf(o[2]) | ((uint)f2bf(o[3]) << 16);
    u.z = (uint)f2bf(o[4]) | ((uint)f2bf(o[5]) << 16);
    u.w = (uint)f2bf(o[6]) | ((uint)f2bf(o[7]) << 16);
    ((uint4*)(outbf + (size_t)node * FEAT))[lane] = u;
}

// ---- final FC (128 -> 10, bf16 in) + log_softmax; THREAD per node ----
__global__ __launch_bounds__(256) void fc_kernel(
    const ushort* __restrict__ hbf, const float* __restrict__ fcW,
    const float* __restrict__ fcb, float* __restrict__ out)
{
    __shared__ float WT[10][FEAT];   // 5 KiB
    __shared__ float bl[10];
    int t = threadIdx.x;
    for (int i = t; i < FEAT * 10; i += 256) {
        int k = i / 10, c = i % 10;
        WT[c][k] = fcW[i];
    }
    if (t < 10) bl[t] = fcb[t];
    __syncthreads();
    int n = blockIdx.x * 256 + t;
    if (n >= NN) return;
    const uint4* row = (const uint4*)(hbf + (size_t)n * FEAT);
    float lg[10];
    #pragma unroll
    for (int c = 0; c < 10; ++c) lg[c] = bl[c];
    #pragma unroll 4
    for (int k8 = 0; k8 < 16; ++k8) {
        uint4 u = row[k8];
        float x0 = bf_lo(u.x), x1 = bf_hi(u.x), x2 = bf_lo(u.y), x3 = bf_hi(u.y);
        float x4 = bf_lo(u.z), x5 = bf_hi(u.z), x6 = bf_lo(u.w), x7 = bf_hi(u.w);
        #pragma unroll
        for (int c = 0; c < 10; ++c) {
            const float* wr = &WT[c][k8 * 8];
            float4 wa = *(const float4*)(wr);
            float4 wb = *(const float4*)(wr + 4);
            float acc = fmaf(x0, wa.x, fmaf(x1, wa.y, fmaf(x2, wa.z, x3 * wa.w)));
            acc = fmaf(x4, wb.x, fmaf(x5, wb.y, fmaf(x6, wb.z, fmaf(x7, wb.w, acc))));
            lg[c] += acc;
        }
    }
    float mx = lg[0];
    #pragma unroll
    for (int c = 1; c < 10; ++c) mx = fmaxf(mx, lg[c]);
    float se = 0.f;
    #pragma unroll
    for (int c = 0; c < 10; ++c) se += __expf(lg[c] - mx);
    float lse = mx + __logf(se);
    float2* op = (float2*)(out + (size_t)n * 10);
    #pragma unroll
    for (int c = 0; c < 5; ++c)
        op[c] = make_float2(lg[2*c] - lse, lg[2*c + 1] - lse);
}

extern "C" void kernel_launch(void* const* d_in, const int* in_sizes, int n_in,
                              void* d_out, int out_size, void* d_ws, size_t ws_size,
                              hipStream_t stream)
{
    const float* x   = (const float*)d_in[0];
    const int*   ei  = (const int*)d_in[1];
    const float* W[3]   = {(const float*)d_in[2], (const float*)d_in[6],  (const float*)d_in[10]};
    const float* asr[3] = {(const float*)d_in[3], (const float*)d_in[7],  (const float*)d_in[11]};
    const float* ads[3] = {(const float*)d_in[4], (const float*)d_in[8],  (const float*)d_in[12]};
    const float* bs[3]  = {(const float*)d_in[5], (const float*)d_in[9],  (const float*)d_in[13]};
    const float* fcW = (const float*)d_in[14];
    const float* fcb = (const float*)d_in[15];
    const int E  = in_sizes[1] / 2;
    const int EP = E + NN;

    // workspace layout
    ushort* xbf  = (ushort*)d_ws;                      // [NN*FEAT] bf16 (layer-0 in)
    ushort* hbf  = xbf + (size_t)NN * FEAT;            // [NN*FEAT] bf16 (gemm out)
    ushort* ybf  = hbf + (size_t)NN * FEAT;            // [NN*FEAT] bf16 (aggr out)
    float* als   = (float*)(ybf + (size_t)NN * FEAT);  // [NN*4]
    float* ald   = als + (size_t)NN * NHEAD;           // [NN*4]
    int* row_ptr = (int*)(ald + (size_t)NN * NHEAD);   // [NN+1]
    int* bsize   = row_ptr + NN + 1;                   // [NBUCK]
    int* bbase   = bsize + NBUCK;                      // [NBUCK+1]
    int* bcursor = bbase + NBUCK + 1;                  // [NBUCK]
    int2* pairs  = (int2*)(bcursor + NBUCK);           // [EP]
    int* colidx  = (int*)(pairs + (size_t)EP);         // [EP]

    // ---- CSR build (once; graph is layer-invariant) ----
    zero_small_kernel<<<1, 256, 0, stream>>>(bsize);
    bucket_hist_kernel<<<1024, 256, 0, stream>>>(ei, E, bsize);
    bucket_scan_kernel<<<1, 256, 0, stream>>>(bsize, bbase, bcursor);
    phaseA_bin_kernel<<<(EP + 256*PA_EPT - 1) / (256*PA_EPT), 256, 0, stream>>>(ei, E, bcursor, pairs);
    phaseB_kernel<<<NBUCK, 256, 0, stream>>>(pairs, bbase, row_ptr, colidx, EP);

    convert_bf_kernel<<<(NN * FEAT / 4 + 255) / 256, 256, 0, stream>>>(x, xbf);

    const ushort* fin = xbf;
    for (int l = 0; l < 3; ++l) {
        gemm_mfma_kernel<<<512, 256, 0, stream>>>(fin, W[l], asr[l], ads[l], hbf, als, ald);
        aggr_csr_kernel<<<(NN + 15) / 16, 256, 0, stream>>>(row_ptr, colidx, hbf, als, ald, bs[l], ybf);
        fin = ybf;
    }
    fc_kernel<<<(NN + 255) / 256, 256, 0, stream>>>(ybf, fcW, fcb, (float*)d_out);
}

// Round 12
// 493.713 us; speedup vs baseline: 1.0488x; 1.0488x over previous
//
#include <hip/hip_runtime.h>
#include <math.h>

#define NN 100000
#define FEAT 128
#define NHEAD 4
#define BSH 9                      // 512 nodes per bucket
#define BNODES 512
#define NBUCK 196                  // ceil(NN / 512)
#define BCAP 16384                 // colidx LDS image capacity (avg span ~8700)
#define PA_EPT 16                  // phase-A edges per thread
#define GTILES 6250                // 100000 / 16
#define HSTRIDE 136                // h-staging row stride (ushorts): 272B = 16B-aligned, bank-rotated
#define SRCMASK 0x1FFFF            // low 17 bits: src id (NN < 2^17)

typedef unsigned int uint;
typedef unsigned short ushort;
typedef __attribute__((ext_vector_type(8))) short short8;
typedef __attribute__((ext_vector_type(4))) float fx4;

__device__ __forceinline__ float lrelu(float v) { return v > 0.f ? v : 0.2f * v; }

__device__ __forceinline__ ushort f2bf(float f) {          // RNE bf16
    uint u = __float_as_uint(f);
    return (ushort)((u + 0x7fffu + ((u >> 16) & 1u)) >> 16);
}
__device__ __forceinline__ float bf_lo(uint u) { return __uint_as_float(u << 16); }
__device__ __forceinline__ float bf_hi(uint u) { return __uint_as_float(u & 0xffff0000u); }

__device__ __forceinline__ short8 pack8f(const float* p) {
    float4 a = *(const float4*)p, b = *(const float4*)(p + 4);
    short8 v;
    v[0] = (short)f2bf(a.x); v[1] = (short)f2bf(a.y);
    v[2] = (short)f2bf(a.z); v[3] = (short)f2bf(a.w);
    v[4] = (short)f2bf(b.x); v[5] = (short)f2bf(b.y);
    v[6] = (short)f2bf(b.z); v[7] = (short)f2bf(b.w);
    return v;
}

// ---- MFMA GEMM: h(bf16) = in @ W, + per-node logits al_src/al_dst ----
// r9 structure (A=W^T in VGPRs, LDS store-staging, no B-prefetch — prefetch
// variants regressed twice, r8/r11). FP32IN: layer-0 reads fp32 x directly.
template <bool FP32IN>
__global__ __launch_bounds__(256, 2) void gemm_mfma_kernel(
    const void* __restrict__ in, const float* __restrict__ W,
    const float* __restrict__ a_src, const float* __restrict__ a_dst,
    ushort* __restrict__ hbf, float* __restrict__ al_s, float* __restrict__ al_d)
{
    __shared__ __align__(16) ushort WA[FEAT * FEAT];       // 32 KiB, fragment-ordered
    __shared__ __align__(16) ushort HS[4][16 * HSTRIDE];   // 17 KiB, per-wave h staging
    const int t = threadIdx.x;
    for (int idx = t; idx < FEAT * FEAT; idx += 256) {
        int k = idx >> 7, m = idx & 127;
        int mt = m >> 4, kt = k >> 5, qq = (k >> 3) & 3, j = k & 7;
        int ln = qq * 16 + (m & 15);
        WA[((mt * 4 + kt) * 64 + ln) * 8 + j] = f2bf(W[idx]);
    }
    __syncthreads();

    const int wv = t >> 6, lane = t & 63;
    const int node_l = lane & 15, q = lane >> 4;

    short8 afr[8][4];
    #pragma unroll
    for (int mt = 0; mt < 8; ++mt)
        #pragma unroll
        for (int kt = 0; kt < 4; ++kt)
            afr[mt][kt] = *(const short8*)&WA[((mt * 4 + kt) * 64 + lane) * 8];

    const ushort* inbf = (const ushort*)in;
    const float*  inf  = (const float*)in;

    for (int tile = blockIdx.x * 4 + wv; tile < GTILES; tile += gridDim.x * 4) {
        const int n0 = tile * 16;
        short8 b0, b1, b2, b3;
        if (FP32IN) {
            const float* rf = inf + (size_t)(n0 + node_l) * FEAT + q * 8;
            b0 = pack8f(rf);
            b1 = pack8f(rf + 32);
            b2 = pack8f(rf + 64);
            b3 = pack8f(rf + 96);
        } else {
            const ushort* rowp = inbf + (size_t)(n0 + node_l) * FEAT + q * 8;
            b0 = *(const short8*)(rowp);
            b1 = *(const short8*)(rowp + 32);
            b2 = *(const short8*)(rowp + 64);
            b3 = *(const short8*)(rowp + 96);
        }
        fx4 zero = {0.f, 0.f, 0.f, 0.f};
        fx4 acc[8];
        #pragma unroll
        for (int mt = 0; mt < 8; ++mt) acc[mt] = zero;
        #pragma unroll
        for (int kt = 0; kt < 4; ++kt) {
            short8 b = (kt == 0) ? b0 : (kt == 1) ? b1 : (kt == 2) ? b2 : b3;
            #pragma unroll
            for (int mt = 0; mt < 8; ++mt)
                acc[mt] = __builtin_amdgcn_mfma_f32_16x16x32_bf16(afr[mt][kt], b, acc[mt], 0, 0, 0);
        }
        // epilogue: logits + stage h into per-wave LDS tile
        float ps[4] = {0.f, 0.f, 0.f, 0.f};
        float pd[4] = {0.f, 0.f, 0.f, 0.f};
        #pragma unroll
        for (int mt = 0; mt < 8; ++mt) {
            float4 as4 = *(const float4*)(a_src + mt * 16 + q * 4);
            float4 ad4 = *(const float4*)(a_dst + mt * 16 + q * 4);
            ps[mt >> 1] += acc[mt][0] * as4.x + acc[mt][1] * as4.y + acc[mt][2] * as4.z + acc[mt][3] * as4.w;
            pd[mt >> 1] += acc[mt][0] * ad4.x + acc[mt][1] * ad4.y + acc[mt][2] * ad4.z + acc[mt][3] * ad4.w;
            ushort4 hv;
            hv.x = f2bf(acc[mt][0]); hv.y = f2bf(acc[mt][1]);
            hv.z = f2bf(acc[mt][2]); hv.w = f2bf(acc[mt][3]);
            *(ushort4*)&HS[wv][node_l * HSTRIDE + mt * 16 + q * 4] = hv;
        }
        #pragma unroll
        for (int h = 0; h < 4; ++h) {
            ps[h] += __shfl_xor(ps[h], 16); ps[h] += __shfl_xor(ps[h], 32);
            pd[h] += __shfl_xor(pd[h], 16); pd[h] += __shfl_xor(pd[h], 32);
        }
        float vs = (q == 0) ? ps[0] : (q == 1) ? ps[1] : (q == 2) ? ps[2] : ps[3];
        float vd = (q == 0) ? pd[0] : (q == 1) ? pd[1] : (q == 2) ? pd[2] : pd[3];
        al_s[(n0 + node_l) * 4 + q] = vs;
        al_d[(n0 + node_l) * 4 + q] = vd;
        // copy-out: wave-private LDS -> 4x fully-coalesced 1KB global stores
        #pragma unroll
        for (int it = 0; it < 4; ++it) {
            int fi = it * 64 + lane;               // 16B chunk index within tile
            int row = fi >> 4, colc = fi & 15;
            short8 v = *(const short8*)&HS[wv][row * HSTRIDE + colc * 8];
            *(short8*)(hbf + (size_t)n0 * FEAT + (size_t)fi * 8) = v;
        }
    }
}

// ======================= CSR build: bucketed counting sort =======================
// pairs packed: (local_dst << 17) | src  (9 + 17 bits)

__global__ void zero_small_kernel(int* bsize)
{
    int t = threadIdx.x;
    if (t < NBUCK) bsize[t] = 0;
}

__global__ __launch_bounds__(256) void bucket_hist_kernel(
    const int* __restrict__ ei, int E, int* bsize)
{
    __shared__ int lh[NBUCK];
    int t = threadIdx.x;
    if (t < NBUCK) lh[t] = 0;
    __syncthreads();
    int stride = gridDim.x * 256;
    for (int i = blockIdx.x * 256 + t; i < E + NN; i += stride) {
        int d = (i < E) ? ei[E + i] : (i - E);
        atomicAdd(&lh[d >> BSH], 1);
    }
    __syncthreads();
    if (t < NBUCK && lh[t]) atomicAdd(&bsize[t], lh[t]);
}

// parallel 256-wide LDS scan over NBUCK entries
__global__ __launch_bounds__(256) void bucket_scan_kernel(
    const int* __restrict__ bsize, int* bbase, int* bcursor)
{
    __shared__ int sm[256];
    int t = threadIdx.x;
    int v = (t < NBUCK) ? bsize[t] : 0;
    sm[t] = v;
    __syncthreads();
    #pragma unroll
    for (int off = 1; off < 256; off <<= 1) {
        int x = (t >= off) ? sm[t - off] : 0;
        __syncthreads();
        sm[t] += x;
        __syncthreads();
    }
    if (t < NBUCK) {
        int excl = sm[t] - v;
        bbase[t] = excl;
        bcursor[t] = excl;
    }
    if (t == 255) bbase[NBUCK] = sm[255];
}

__global__ __launch_bounds__(256) void phaseA_bin_kernel(
    const int* __restrict__ ei, int E, int* bcursor, uint* __restrict__ pairs)
{
    __shared__ int lh[NBUCK], lb[NBUCK];
    int t = threadIdx.x;
    if (t < NBUCK) lh[t] = 0;
    __syncthreads();
    int base = blockIdx.x * (256 * PA_EPT) + t;
    int s[PA_EPT], d[PA_EPT];
    #pragma unroll
    for (int k = 0; k < PA_EPT; ++k) {
        int i = base + k * 256;
        if (i < E)            { s[k] = ei[i]; d[k] = ei[E + i]; }
        else if (i < E + NN)  { s[k] = i - E; d[k] = s[k]; }
        else                  { s[k] = 0; d[k] = -1; }
        if (d[k] >= 0) atomicAdd(&lh[d[k] >> BSH], 1);
    }
    __syncthreads();
    if (t < NBUCK) {
        int c = lh[t];
        lb[t] = c ? atomicAdd(&bcursor[t], c) : 0;
        lh[t] = 0;
    }
    __syncthreads();
    #pragma unroll
    for (int k = 0; k < PA_EPT; ++k) {
        if (d[k] >= 0) {
            int b = d[k] >> BSH;
            int off = atomicAdd(&lh[b], 1);
            pairs[lb[b] + off] = ((uint)(d[k] & (BNODES - 1)) << 17) | (uint)s[k];
        }
    }
}

__global__ __launch_bounds__(256) void phaseB_kernel(
    const uint* __restrict__ pairs, const int* __restrict__ bbase,
    int* __restrict__ row_ptr, int* __restrict__ colidx, int EP)
{
    __shared__ int nh[BNODES];
    __shared__ int ex[BNODES];
    __shared__ int ss[256];
    __shared__ int img[BCAP];
    int b = blockIdx.x, t = threadIdx.x;
    int node0 = b << BSH;
    int nend = min(NN - node0, BNODES);
    int pb = bbase[b], pe = bbase[b + 1];
    int span = pe - pb;
    for (int j = t; j < BNODES; j += 256) nh[j] = 0;
    __syncthreads();
    for (int i = t; i < span; i += 256)
        atomicAdd(&nh[pairs[pb + i] >> 17], 1);
    __syncthreads();
    int v0 = nh[2 * t], v1 = nh[2 * t + 1];
    int psc = v0 + v1;
    ss[t] = psc;
    __syncthreads();
    #pragma unroll
    for (int off = 1; off < 256; off <<= 1) {
        int x = (t >= off) ? ss[t - off] : 0;
        __syncthreads();
        ss[t] += x;
        __syncthreads();
    }
    int ep = ss[t] - psc;
    ex[2 * t] = ep;
    ex[2 * t + 1] = ep + v0;
    __syncthreads();
    for (int j = t; j < nend; j += 256) row_ptr[node0 + j] = pb + ex[j];
    if (b == NBUCK - 1 && t == 0) row_ptr[NN] = EP;
    for (int j = t; j < BNODES; j += 256) nh[j] = ex[j];   // reuse as cursors
    __syncthreads();
    if (span <= BCAP) {
        for (int i = t; i < span; i += 256) {
            uint p = pairs[pb + i];
            int pos = atomicAdd(&nh[p >> 17], 1);
            img[pos] = (int)(p & SRCMASK);
        }
        __syncthreads();
        for (int i = t; i < span; i += 256) colidx[pb + i] = img[i];
    } else {
        for (int i = t; i < span; i += 256) {
            uint p = pairs[pb + i];
            int pos = atomicAdd(&nh[p >> 17], 1);
            colidx[pb + pos] = (int)(p & SRCMASK);
        }
    }
}

// ======================= fused softmax + aggregation (bf16 out) =======================
#define AGGR_STEP(hv, wgt)                                                    \
    a0 = fmaf(wgt, bf_lo(hv.x), a0); a1 = fmaf(wgt, bf_hi(hv.x), a1);        \
    a2 = fmaf(wgt, bf_lo(hv.y), a2); a3 = fmaf(wgt, bf_hi(hv.y), a3);        \
    a4 = fmaf(wgt, bf_lo(hv.z), a4); a5 = fmaf(wgt, bf_hi(hv.z), a5);        \
    a6 = fmaf(wgt, bf_lo(hv.w), a6); a7 = fmaf(wgt, bf_hi(hv.w), a7);

#define PROC4(cv)                                                             \
    {                                                                         \
        int s0 = cv.x, s1 = cv.y, s2 = cv.z, s3 = cv.w;                       \
        float w0 = __expf(lrelu(al_s[s0*4 + head] + ald_h));                  \
        float w1 = __expf(lrelu(al_s[s1*4 + head] + ald_h));                  \
        float w2 = __expf(lrelu(al_s[s2*4 + head] + ald_h));                  \
        float w3 = __expf(lrelu(al_s[s3*4 + head] + ald_h));                  \
        uint4 h0 = ((const uint4*)(hbf + (size_t)s0 * FEAT))[lane];           \
        uint4 h1 = ((const uint4*)(hbf + (size_t)s1 * FEAT))[lane];           \
        uint4 h2 = ((const uint4*)(hbf + (size_t)s2 * FEAT))[lane];           \
        uint4 h3 = ((const uint4*)(hbf + (size_t)s3 * FEAT))[lane];           \
        ssum += (w0 + w1) + (w2 + w3);                                        \
        AGGR_STEP(h0, w0) AGGR_STEP(h1, w1) AGGR_STEP(h2, w2) AGGR_STEP(h3, w3) \
    }

__global__ __launch_bounds__(256) void aggr_csr_kernel(
    const int* __restrict__ row_ptr, const int* __restrict__ colidx,
    const ushort* __restrict__ hbf, const float* __restrict__ al_s,
    const float* __restrict__ al_d, const float* __restrict__ bias,
    ushort* __restrict__ outbf)
{
    int t = threadIdx.x;
    int node = blockIdx.x * 16 + (t >> 4);
    if (node >= NN) return;
    int lane = t & 15;
    int head = lane >> 2;
    float ald_h = al_d[node * 4 + head];
    int beg = row_ptr[node], end = row_ptr[node + 1];

    float ssum = 0.f;
    float a0=0.f,a1=0.f,a2=0.f,a3=0.f,a4=0.f,a5=0.f,a6=0.f,a7=0.f;

    int p = beg;
    int4 ca;
    if (p + 4 <= end) ca = *(const int4*)&colidx[p];
    while (p + 8 <= end) {
        int4 na = *(const int4*)&colidx[p + 4];   // prefetch next batch
        PROC4(ca)
        ca = na;
        p += 4;
    }
    if (p + 4 <= end) { PROC4(ca) p += 4; }
    for (; p < end; ++p) {
        int sn = colidx[p];
        float wq = __expf(lrelu(al_s[sn*4 + head] + ald_h));
        uint4 hv = ((const uint4*)(hbf + (size_t)sn * FEAT))[lane];
        ssum += wq;
        AGGR_STEP(hv, wq)
    }
    float inv = 1.f / (ssum + 1e-16f);
    const float* bp = bias + lane * 8;
    float o[8] = {a0,a1,a2,a3,a4,a5,a6,a7};
    #pragma unroll
    for (int k = 0; k < 8; ++k) {
        float v = o[k] * inv + bp[k];
        o[k] = v > 0.f ? v : __expf(v) - 1.f;
    }
    uint4 u;
    u.x = (uint)f2bf(o[0]) | ((uint)f2bf(o[1]) << 16);
    u.y = (uint)f2bf(o[2]) | ((uint)f2bf(o[3]) << 16);
    u.z = (uint)f2bf(o[4]) | ((uint)f2bf(o[5]) << 16);
    u.w = (uint)f2bf(o[6]) | ((uint)f2bf(o[7]) << 16);
    ((uint4*)(outbf + (size_t)node * FEAT))[lane] = u;
}

// ---- final FC (128 -> 10, bf16 in) + log_softmax; THREAD per node ----
__global__ __launch_bounds__(256) void fc_kernel(
    const ushort* __restrict__ hbf, const float* __restrict__ fcW,
    const float* __restrict__ fcb, float* __restrict__ out)
{
    __shared__ float WT[10][FEAT];   // 5 KiB
    __shared__ float bl[10];
    int t = threadIdx.x;
    for (int i = t; i < FEAT * 10; i += 256) {
        int k = i / 10, c = i % 10;
        WT[c][k] = fcW[i];
    }
    if (t < 10) bl[t] = fcb[t];
    __syncthreads();
    int n = blockIdx.x * 256 + t;
    if (n >= NN) return;
    const uint4* row = (const uint4*)(hbf + (size_t)n * FEAT);
    float lg[10];
    #pragma unroll
    for (int c = 0; c < 10; ++c) lg[c] = bl[c];
    #pragma unroll 4
    for (int k8 = 0; k8 < 16; ++k8) {
        uint4 u = row[k8];
        float x0 = bf_lo(u.x), x1 = bf_hi(u.x), x2 = bf_lo(u.y), x3 = bf_hi(u.y);
        float x4 = bf_lo(u.z), x5 = bf_hi(u.z), x6 = bf_lo(u.w), x7 = bf_hi(u.w);
        #pragma unroll
        for (int c = 0; c < 10; ++c) {
            const float* wr = &WT[c][k8 * 8];
            float4 wa = *(const float4*)(wr);
            float4 wb = *(const float4*)(wr + 4);
            float acc = fmaf(x0, wa.x, fmaf(x1, wa.y, fmaf(x2, wa.z, x3 * wa.w)));
            acc = fmaf(x4, wb.x, fmaf(x5, wb.y, fmaf(x6, wb.z, fmaf(x7, wb.w, acc))));
            lg[c] += acc;
        }
    }
    float mx = lg[0];
    #pragma unroll
    for (int c = 1; c < 10; ++c) mx = fmaxf(mx, lg[c]);
    float se = 0.f;
    #pragma unroll
    for (int c = 0; c < 10; ++c) se += __expf(lg[c] - mx);
    float lse = mx + __logf(se);
    float2* op = (float2*)(out + (size_t)n * 10);
    #pragma unroll
    for (int c = 0; c < 5; ++c)
        op[c] = make_float2(lg[2*c] - lse, lg[2*c + 1] - lse);
}

extern "C" void kernel_launch(void* const* d_in, const int* in_sizes, int n_in,
                              void* d_out, int out_size, void* d_ws, size_t ws_size,
                              hipStream_t stream)
{
    const float* x   = (const float*)d_in[0];
    const int*   ei  = (const int*)d_in[1];
    const float* W[3]   = {(const float*)d_in[2], (const float*)d_in[6],  (const float*)d_in[10]};
    const float* asr[3] = {(const float*)d_in[3], (const float*)d_in[7],  (const float*)d_in[11]};
    const float* ads[3] = {(const float*)d_in[4], (const float*)d_in[8],  (const float*)d_in[12]};
    const float* bs[3]  = {(const float*)d_in[5], (const float*)d_in[9],  (const float*)d_in[13]};
    const float* fcW = (const float*)d_in[14];
    const float* fcb = (const float*)d_in[15];
    const int E  = in_sizes[1] / 2;
    const int EP = E + NN;

    // workspace layout
    ushort* hbf  = (ushort*)d_ws;                      // [NN*FEAT] bf16 (gemm out)
    ushort* ybf  = hbf + (size_t)NN * FEAT;            // [NN*FEAT] bf16 (aggr out)
    float* als   = (float*)(ybf + (size_t)NN * FEAT);  // [NN*4]
    float* ald   = als + (size_t)NN * NHEAD;           // [NN*4]
    int* row_ptr = (int*)(ald + (size_t)NN * NHEAD);   // [NN+1]
    int* bsize   = row_ptr + NN + 1;                   // [NBUCK]
    int* bbase   = bsize + NBUCK;                      // [NBUCK+1]
    int* bcursor = bbase + NBUCK + 1;                  // [NBUCK]
    uint* pairs  = (uint*)(bcursor + NBUCK);           // [EP] packed
    int* colidx  = (int*)(pairs + (size_t)EP);         // [EP]

    // ---- CSR build (once; graph is layer-invariant) ----
    zero_small_kernel<<<1, 256, 0, stream>>>(bsize);
    bucket_hist_kernel<<<1024, 256, 0, stream>>>(ei, E, bsize);
    bucket_scan_kernel<<<1, 256, 0, stream>>>(bsize, bbase, bcursor);
    phaseA_bin_kernel<<<(EP + 256*PA_EPT - 1) / (256*PA_EPT), 256, 0, stream>>>(ei, E, bcursor, pairs);
    phaseB_kernel<<<NBUCK, 256, 0, stream>>>(pairs, bbase, row_ptr, colidx, EP);

    // layer 0 (fp32 input, converted in-register inside gemm)
    gemm_mfma_kernel<true><<<512, 256, 0, stream>>>(x, W[0], asr[0], ads[0], hbf, als, ald);
    aggr_csr_kernel<<<(NN + 15) / 16, 256, 0, stream>>>(row_ptr, colidx, hbf, als, ald, bs[0], ybf);
    // layers 1,2 (bf16 input)
    for (int l = 1; l < 3; ++l) {
        gemm_mfma_kernel<false><<<512, 256, 0, stream>>>(ybf, W[l], asr[l], ads[l], hbf, als, ald);
        aggr_csr_kernel<<<(NN + 15) / 16, 256, 0, stream>>>(row_ptr, colidx, hbf, als, ald, bs[l], ybf);
    }
    fc_kernel<<<(NN + 255) / 256, 256, 0, stream>>>(ybf, fcW, fcb, (float*)d_out);
}

// Round 13
// 479.424 us; speedup vs baseline: 1.0801x; 1.0298x over previous
//
#include <hip/hip_runtime.h>
#include <math.h>

#define NN 100000
#define FEAT 128
#define NHEAD 4
#define BSH 9                      // 512 nodes per bucket
#define BNODES 512
#define NBUCK 196                  // ceil(NN / 512)
#define BCAP 16384                 // colidx LDS image capacity (avg span ~8700)
#define PA_EPT 16                  // phase-A edges per thread
#define GTILES 6250                // 100000 / 16
#define GEMMB 512                  // gemm grid blocks
#define HSTRIDE 136                // h-staging row stride (ushorts)
#define SRCMASK 0x1FFFF            // low 17 bits: src id (NN < 2^17)

typedef unsigned int uint;
typedef unsigned short ushort;
typedef __attribute__((ext_vector_type(8))) short short8;
typedef __attribute__((ext_vector_type(4))) float fx4;

__device__ __forceinline__ float lrelu(float v) { return v > 0.f ? v : 0.2f * v; }

__device__ __forceinline__ ushort f2bf(float f) {          // RNE bf16
    uint u = __float_as_uint(f);
    return (ushort)((u + 0x7fffu + ((u >> 16) & 1u)) >> 16);
}
__device__ __forceinline__ float bf_lo(uint u) { return __uint_as_float(u << 16); }
__device__ __forceinline__ float bf_hi(uint u) { return __uint_as_float(u & 0xffff0000u); }

__device__ __forceinline__ short8 pack8f(const float* p) {
    float4 a = *(const float4*)p, b = *(const float4*)(p + 4);
    short8 v;
    v[0] = (short)f2bf(a.x); v[1] = (short)f2bf(a.y);
    v[2] = (short)f2bf(a.z); v[3] = (short)f2bf(a.w);
    v[4] = (short)f2bf(b.x); v[5] = (short)f2bf(b.y);
    v[6] = (short)f2bf(b.z); v[7] = (short)f2bf(b.w);
    return v;
}

// ---- MFMA GEMM body (r12 structure; no B-prefetch — regressed twice r8/r11) ----
template <bool FP32IN>
__device__ __forceinline__ void gemm_body(
    const void* __restrict__ in, const float* __restrict__ W,
    const float* __restrict__ a_src, const float* __restrict__ a_dst,
    ushort* __restrict__ hbf, float* __restrict__ al_s, float* __restrict__ al_d,
    int bid, int gridn)
{
    __shared__ __align__(16) ushort WA[FEAT * FEAT];       // 32 KiB, fragment-ordered
    __shared__ __align__(16) ushort HS[4][16 * HSTRIDE];   // 17 KiB, per-wave h staging
    const int t = threadIdx.x;
    for (int idx = t; idx < FEAT * FEAT; idx += 256) {
        int k = idx >> 7, m = idx & 127;
        int mt = m >> 4, kt = k >> 5, qq = (k >> 3) & 3, j = k & 7;
        int ln = qq * 16 + (m & 15);
        WA[((mt * 4 + kt) * 64 + ln) * 8 + j] = f2bf(W[idx]);
    }
    __syncthreads();

    const int wv = t >> 6, lane = t & 63;
    const int node_l = lane & 15, q = lane >> 4;

    short8 afr[8][4];
    #pragma unroll
    for (int mt = 0; mt < 8; ++mt)
        #pragma unroll
        for (int kt = 0; kt < 4; ++kt)
            afr[mt][kt] = *(const short8*)&WA[((mt * 4 + kt) * 64 + lane) * 8];

    const ushort* inbf = (const ushort*)in;
    const float*  inf  = (const float*)in;

    for (int tile = bid * 4 + wv; tile < GTILES; tile += gridn * 4) {
        const int n0 = tile * 16;
        short8 b0, b1, b2, b3;
        if (FP32IN) {
            const float* rf = inf + (size_t)(n0 + node_l) * FEAT + q * 8;
            b0 = pack8f(rf);
            b1 = pack8f(rf + 32);
            b2 = pack8f(rf + 64);
            b3 = pack8f(rf + 96);
        } else {
            const ushort* rowp = inbf + (size_t)(n0 + node_l) * FEAT + q * 8;
            b0 = *(const short8*)(rowp);
            b1 = *(const short8*)(rowp + 32);
            b2 = *(const short8*)(rowp + 64);
            b3 = *(const short8*)(rowp + 96);
        }
        fx4 zero = {0.f, 0.f, 0.f, 0.f};
        fx4 acc[8];
        #pragma unroll
        for (int mt = 0; mt < 8; ++mt) acc[mt] = zero;
        #pragma unroll
        for (int kt = 0; kt < 4; ++kt) {
            short8 b = (kt == 0) ? b0 : (kt == 1) ? b1 : (kt == 2) ? b2 : b3;
            #pragma unroll
            for (int mt = 0; mt < 8; ++mt)
                acc[mt] = __builtin_amdgcn_mfma_f32_16x16x32_bf16(afr[mt][kt], b, acc[mt], 0, 0, 0);
        }
        float ps[4] = {0.f, 0.f, 0.f, 0.f};
        float pd[4] = {0.f, 0.f, 0.f, 0.f};
        #pragma unroll
        for (int mt = 0; mt < 8; ++mt) {
            float4 as4 = *(const float4*)(a_src + mt * 16 + q * 4);
            float4 ad4 = *(const float4*)(a_dst + mt * 16 + q * 4);
            ps[mt >> 1] += acc[mt][0] * as4.x + acc[mt][1] * as4.y + acc[mt][2] * as4.z + acc[mt][3] * as4.w;
            pd[mt >> 1] += acc[mt][0] * ad4.x + acc[mt][1] * ad4.y + acc[mt][2] * ad4.z + acc[mt][3] * ad4.w;
            ushort4 hv;
            hv.x = f2bf(acc[mt][0]); hv.y = f2bf(acc[mt][1]);
            hv.z = f2bf(acc[mt][2]); hv.w = f2bf(acc[mt][3]);
            *(ushort4*)&HS[wv][node_l * HSTRIDE + mt * 16 + q * 4] = hv;
        }
        #pragma unroll
        for (int h = 0; h < 4; ++h) {
            ps[h] += __shfl_xor(ps[h], 16); ps[h] += __shfl_xor(ps[h], 32);
            pd[h] += __shfl_xor(pd[h], 16); pd[h] += __shfl_xor(pd[h], 32);
        }
        float vs = (q == 0) ? ps[0] : (q == 1) ? ps[1] : (q == 2) ? ps[2] : ps[3];
        float vd = (q == 0) ? pd[0] : (q == 1) ? pd[1] : (q == 2) ? pd[2] : pd[3];
        al_s[(n0 + node_l) * 4 + q] = vs;
        al_d[(n0 + node_l) * 4 + q] = vd;
        #pragma unroll
        for (int it = 0; it < 4; ++it) {
            int fi = it * 64 + lane;
            int row = fi >> 4, colc = fi & 15;
            short8 v = *(const short8*)&HS[wv][row * HSTRIDE + colc * 8];
            *(short8*)(hbf + (size_t)n0 * FEAT + (size_t)fi * 8) = v;
        }
    }
}

// ---- phase-A body: bucket-binned (dst,src) pair scatter ----
__device__ __forceinline__ void phaseA_body(
    const int* __restrict__ ei, int E, int* bcursor, uint* __restrict__ pairs, int bid)
{
    __shared__ int lh[NBUCK], lb[NBUCK];
    int t = threadIdx.x;
    if (t < NBUCK) lh[t] = 0;
    __syncthreads();
    int base = bid * (256 * PA_EPT) + t;
    int s[PA_EPT], d[PA_EPT];
    #pragma unroll
    for (int k = 0; k < PA_EPT; ++k) {
        int i = base + k * 256;
        if (i < E)            { s[k] = ei[i]; d[k] = ei[E + i]; }
        else if (i < E + NN)  { s[k] = i - E; d[k] = s[k]; }
        else                  { s[k] = 0; d[k] = -1; }
        if (d[k] >= 0) atomicAdd(&lh[d[k] >> BSH], 1);
    }
    __syncthreads();
    if (t < NBUCK) {
        int c = lh[t];
        lb[t] = c ? atomicAdd(&bcursor[t], c) : 0;
        lh[t] = 0;
    }
    __syncthreads();
    #pragma unroll
    for (int k = 0; k < PA_EPT; ++k) {
        if (d[k] >= 0) {
            int b = d[k] >> BSH;
            int off = atomicAdd(&lh[b], 1);
            pairs[lb[b] + off] = ((uint)(d[k] & (BNODES - 1)) << 17) | (uint)s[k];
        }
    }
}

// ---- standalone gemm (layers 1,2) ----
__global__ __launch_bounds__(256, 2) void gemm_mfma_kernel(
    const void* __restrict__ in, const float* __restrict__ W,
    const float* __restrict__ a_src, const float* __restrict__ a_dst,
    ushort* __restrict__ hbf, float* __restrict__ al_s, float* __restrict__ al_d)
{
    gemm_body<false>(in, W, a_src, a_dst, hbf, al_s, al_d, blockIdx.x, GEMMB);
}

// ---- fused: gemm layer 0 (fp32 in) || CSR phase A (data-independent) ----
__global__ __launch_bounds__(256, 2) void gemm0_phaseA_kernel(
    const float* __restrict__ x, const float* __restrict__ W,
    const float* __restrict__ a_src, const float* __restrict__ a_dst,
    ushort* __restrict__ hbf, float* __restrict__ al_s, float* __restrict__ al_d,
    const int* __restrict__ ei, int E, int* bcursor, uint* __restrict__ pairs)
{
    if (blockIdx.x < GEMMB)
        gemm_body<true>(x, W, a_src, a_dst, hbf, al_s, al_d, blockIdx.x, GEMMB);
    else
        phaseA_body(ei, E, bcursor, pairs, blockIdx.x - GEMMB);
}

// ======================= CSR build (rest) =======================

__global__ __launch_bounds__(256) void bucket_hist_kernel(
    const int* __restrict__ ei, int E, int* bsize)
{
    __shared__ int lh[NBUCK];
    int t = threadIdx.x;
    if (t < NBUCK) lh[t] = 0;
    __syncthreads();
    int stride = gridDim.x * 256;
    for (int i = blockIdx.x * 256 + t; i < E + NN; i += stride) {
        int d = (i < E) ? ei[E + i] : (i - E);
        atomicAdd(&lh[d >> BSH], 1);
    }
    __syncthreads();
    if (t < NBUCK && lh[t]) atomicAdd(&bsize[t], lh[t]);
}

__global__ __launch_bounds__(256) void bucket_scan_kernel(
    const int* __restrict__ bsize, int* bbase, int* bcursor)
{
    __shared__ int sm[256];
    int t = threadIdx.x;
    int v = (t < NBUCK) ? bsize[t] : 0;
    sm[t] = v;
    __syncthreads();
    #pragma unroll
    for (int off = 1; off < 256; off <<= 1) {
        int x = (t >= off) ? sm[t - off] : 0;
        __syncthreads();
        sm[t] += x;
        __syncthreads();
    }
    if (t < NBUCK) {
        int excl = sm[t] - v;
        bbase[t] = excl;
        bcursor[t] = excl;
    }
    if (t == 255) bbase[NBUCK] = sm[255];
}

__global__ __launch_bounds__(256) void phaseB_kernel(
    const uint* __restrict__ pairs, const int* __restrict__ bbase,
    int* __restrict__ row_ptr, int* __restrict__ colidx, int EP)
{
    __shared__ int nh[BNODES];
    __shared__ int ex[BNODES];
    __shared__ int ss[256];
    __shared__ int img[BCAP];
    int b = blockIdx.x, t = threadIdx.x;
    int node0 = b << BSH;
    int nend = min(NN - node0, BNODES);
    int pb = bbase[b], pe = bbase[b + 1];
    int span = pe - pb;
    for (int j = t; j < BNODES; j += 256) nh[j] = 0;
    __syncthreads();
    for (int i = t; i < span; i += 256)
        atomicAdd(&nh[pairs[pb + i] >> 17], 1);
    __syncthreads();
    int v0 = nh[2 * t], v1 = nh[2 * t + 1];
    int psc = v0 + v1;
    ss[t] = psc;
    __syncthreads();
    #pragma unroll
    for (int off = 1; off < 256; off <<= 1) {
        int x = (t >= off) ? ss[t - off] : 0;
        __syncthreads();
        ss[t] += x;
        __syncthreads();
    }
    int ep = ss[t] - psc;
    ex[2 * t] = ep;
    ex[2 * t + 1] = ep + v0;
    __syncthreads();
    for (int j = t; j < nend; j += 256) row_ptr[node0 + j] = pb + ex[j];
    if (b == NBUCK - 1 && t == 0) row_ptr[NN] = EP;
    for (int j = t; j < BNODES; j += 256) nh[j] = ex[j];   // reuse as cursors
    __syncthreads();
    if (span <= BCAP) {
        for (int i = t; i < span; i += 256) {
            uint p = pairs[pb + i];
            int pos = atomicAdd(&nh[p >> 17], 1);
            img[pos] = (int)(p & SRCMASK);
        }
        __syncthreads();
        for (int i = t; i < span; i += 256) colidx[pb + i] = img[i];
    } else {
        for (int i = t; i < span; i += 256) {
            uint p = pairs[pb + i];
            int pos = atomicAdd(&nh[p >> 17], 1);
            colidx[pb + pos] = (int)(p & SRCMASK);
        }
    }
}

// ======================= fused softmax + aggregation =======================
// LAST=false: writes bf16 y. LAST=true: fuses final FC(128->10)+log_softmax.
#define AGGR_STEP(hv, wgt)                                                    \
    a0 = fmaf(wgt, bf_lo(hv.x), a0); a1 = fmaf(wgt, bf_hi(hv.x), a1);        \
    a2 = fmaf(wgt, bf_lo(hv.y), a2); a3 = fmaf(wgt, bf_hi(hv.y), a3);        \
    a4 = fmaf(wgt, bf_lo(hv.z), a4); a5 = fmaf(wgt, bf_hi(hv.z), a5);        \
    a6 = fmaf(wgt, bf_lo(hv.w), a6); a7 = fmaf(wgt, bf_hi(hv.w), a7);

#define PROC4(cv)                                                             \
    {                                                                         \
        int s0 = cv.x, s1 = cv.y, s2 = cv.z, s3 = cv.w;                       \
        float w0 = __expf(lrelu(al_s[s0*4 + head] + ald_h));                  \
        float w1 = __expf(lrelu(al_s[s1*4 + head] + ald_h));                  \
        float w2 = __expf(lrelu(al_s[s2*4 + head] + ald_h));                  \
        float w3 = __expf(lrelu(al_s[s3*4 + head] + ald_h));                  \
        uint4 h0 = ((const uint4*)(hbf + (size_t)s0 * FEAT))[lane];           \
        uint4 h1 = ((const uint4*)(hbf + (size_t)s1 * FEAT))[lane];           \
        uint4 h2 = ((const uint4*)(hbf + (size_t)s2 * FEAT))[lane];           \
        uint4 h3 = ((const uint4*)(hbf + (size_t)s3 * FEAT))[lane];           \
        ssum += (w0 + w1) + (w2 + w3);                                        \
        AGGR_STEP(h0, w0) AGGR_STEP(h1, w1) AGGR_STEP(h2, w2) AGGR_STEP(h3, w3) \
    }

template <bool LAST>
__global__ __launch_bounds__(256) void aggr_csr_kernel(
    const int* __restrict__ row_ptr, const int* __restrict__ colidx,
    const ushort* __restrict__ hbf, const float* __restrict__ al_s,
    const float* __restrict__ al_d, const float* __restrict__ bias,
    ushort* __restrict__ outbf,
    const float* __restrict__ fcW, const float* __restrict__ fcb,
    float* __restrict__ logout)
{
    __shared__ float WT[10][FEAT];   // used only when LAST
    __shared__ float bl[10];
    int t = threadIdx.x;
    if (LAST) {
        for (int i = t; i < FEAT * 10; i += 256) {
            int k = i / 10, c = i % 10;
            WT[c][k] = fcW[i];
        }
        if (t < 10) bl[t] = fcb[t];
        __syncthreads();
    }
    int node = blockIdx.x * 16 + (t >> 4);
    int lane = t & 15;
    int head = lane >> 2;
    float ald_h = al_d[node * 4 + head];
    int beg = row_ptr[node], end = row_ptr[node + 1];

    float ssum = 0.f;
    float a0=0.f,a1=0.f,a2=0.f,a3=0.f,a4=0.f,a5=0.f,a6=0.f,a7=0.f;

    int p = beg;
    int4 ca;
    if (p + 4 <= end) ca = *(const int4*)&colidx[p];
    while (p + 8 <= end) {
        int4 na = *(const int4*)&colidx[p + 4];   // prefetch next batch
        PROC4(ca)
        ca = na;
        p += 4;
    }
    if (p + 4 <= end) { PROC4(ca) p += 4; }
    for (; p < end; ++p) {
        int sn = colidx[p];
        float wq = __expf(lrelu(al_s[sn*4 + head] + ald_h));
        uint4 hv = ((const uint4*)(hbf + (size_t)sn * FEAT))[lane];
        ssum += wq;
        AGGR_STEP(hv, wq)
    }
    float inv = 1.f / (ssum + 1e-16f);
    const float* bp = bias + lane * 8;
    float o[8] = {a0,a1,a2,a3,a4,a5,a6,a7};
    #pragma unroll
    for (int k = 0; k < 8; ++k) {
        float v = o[k] * inv + bp[k];
        o[k] = v > 0.f ? v : __expf(v) - 1.f;
    }
    if (!LAST) {
        uint4 u;
        u.x = (uint)f2bf(o[0]) | ((uint)f2bf(o[1]) << 16);
        u.y = (uint)f2bf(o[2]) | ((uint)f2bf(o[3]) << 16);
        u.z = (uint)f2bf(o[4]) | ((uint)f2bf(o[5]) << 16);
        u.w = (uint)f2bf(o[6]) | ((uint)f2bf(o[7]) << 16);
        ((uint4*)(outbf + (size_t)node * FEAT))[lane] = u;
    } else {
        // per-lane partial logits over this lane's 8 dims, reduce across 16 lanes
        float lg[10];
        #pragma unroll
        for (int c = 0; c < 10; ++c) {
            const float* wr = &WT[c][lane * 8];
            float4 wa = *(const float4*)(wr);
            float4 wb = *(const float4*)(wr + 4);
            float acc = fmaf(o[0], wa.x, fmaf(o[1], wa.y, fmaf(o[2], wa.z, o[3] * wa.w)));
            acc = fmaf(o[4], wb.x, fmaf(o[5], wb.y, fmaf(o[6], wb.z, fmaf(o[7], wb.w, acc))));
            lg[c] = acc;
        }
        #pragma unroll
        for (int c = 0; c < 10; ++c) {
            lg[c] += __shfl_xor(lg[c], 1, 16);
            lg[c] += __shfl_xor(lg[c], 2, 16);
            lg[c] += __shfl_xor(lg[c], 4, 16);
            lg[c] += __shfl_xor(lg[c], 8, 16);
        }
        if (lane == 0) {
            float mx = -1e30f;
            #pragma unroll
            for (int c = 0; c < 10; ++c) { lg[c] += bl[c]; mx = fmaxf(mx, lg[c]); }
            float se = 0.f;
            #pragma unroll
            for (int c = 0; c < 10; ++c) se += __expf(lg[c] - mx);
            float lse = mx + __logf(se);
            float2* op = (float2*)(logout + (size_t)node * 10);
            #pragma unroll
            for (int c = 0; c < 5; ++c)
                op[c] = make_float2(lg[2*c] - lse, lg[2*c + 1] - lse);
        }
    }
}

extern "C" void kernel_launch(void* const* d_in, const int* in_sizes, int n_in,
                              void* d_out, int out_size, void* d_ws, size_t ws_size,
                              hipStream_t stream)
{
    const float* x   = (const float*)d_in[0];
    const int*   ei  = (const int*)d_in[1];
    const float* W[3]   = {(const float*)d_in[2], (const float*)d_in[6],  (const float*)d_in[10]};
    const float* asr[3] = {(const float*)d_in[3], (const float*)d_in[7],  (const float*)d_in[11]};
    const float* ads[3] = {(const float*)d_in[4], (const float*)d_in[8],  (const float*)d_in[12]};
    const float* bs[3]  = {(const float*)d_in[5], (const float*)d_in[9],  (const float*)d_in[13]};
    const float* fcW = (const float*)d_in[14];
    const float* fcb = (const float*)d_in[15];
    const int E  = in_sizes[1] / 2;
    const int EP = E + NN;

    // workspace layout
    ushort* hbf  = (ushort*)d_ws;                      // [NN*FEAT] bf16 (gemm out)
    ushort* ybf  = hbf + (size_t)NN * FEAT;            // [NN*FEAT] bf16 (aggr out)
    float* als   = (float*)(ybf + (size_t)NN * FEAT);  // [NN*4]
    float* ald   = als + (size_t)NN * NHEAD;           // [NN*4]
    int* row_ptr = (int*)(ald + (size_t)NN * NHEAD);   // [NN+1]
    int* bsize   = row_ptr + NN + 1;                   // [NBUCK]
    int* bbase   = bsize + NBUCK;                      // [NBUCK+1]
    int* bcursor = bbase + NBUCK + 1;                  // [NBUCK]
    uint* pairs  = (uint*)(bcursor + NBUCK);           // [EP] packed
    int* colidx  = (int*)(pairs + (size_t)EP);         // [EP]

    const int pab = (EP + 256 * PA_EPT - 1) / (256 * PA_EPT);

    // ---- CSR build head ----
    hipMemsetAsync(bsize, 0, NBUCK * sizeof(int), stream);
    bucket_hist_kernel<<<1024, 256, 0, stream>>>(ei, E, bsize);
    bucket_scan_kernel<<<1, 256, 0, stream>>>(bsize, bbase, bcursor);

    // ---- layer 0 gemm (fp32 in) overlapped with CSR phase A ----
    gemm0_phaseA_kernel<<<GEMMB + pab, 256, 0, stream>>>(
        x, W[0], asr[0], ads[0], hbf, als, ald, ei, E, bcursor, pairs);
    phaseB_kernel<<<NBUCK, 256, 0, stream>>>(pairs, bbase, row_ptr, colidx, EP);

    aggr_csr_kernel<false><<<(NN + 15) / 16, 256, 0, stream>>>(
        row_ptr, colidx, hbf, als, ald, bs[0], ybf, nullptr, nullptr, nullptr);

    gemm_mfma_kernel<<<GEMMB, 256, 0, stream>>>(ybf, W[1], asr[1], ads[1], hbf, als, ald);
    aggr_csr_kernel<false><<<(NN + 15) / 16, 256, 0, stream>>>(
        row_ptr, colidx, hbf, als, ald, bs[1], ybf, nullptr, nullptr, nullptr);

    gemm_mfma_kernel<<<GEMMB, 256, 0, stream>>>(ybf, W[2], asr[2], ads[2], hbf, als, ald);
    aggr_csr_kernel<true><<<(NN + 15) / 16, 256, 0, stream>>>(
        row_ptr, colidx, hbf, als, ald, bs[2], nullptr, fcW, fcb, (float*)d_out);
}